// Round 9
// baseline (144.037 us; speedup 1.0000x reference)
//
#include <hip/hip_runtime.h>

// center_loss: loss = (1/N) * sum_i ||feature[i] - center_vector[label[i]]||_2
// N=65536, D=512, C=10000, fp32 in/out.
//
// R3 structure (interleaved grid-stride, one wave per sample, 64 lanes x
// 2 float4) + two targeted changes:
//  1. Non-temporal loads on feature (streamed once, zero reuse) so the
//     128 MB stream does not evict the 20 MB center set from L2/LLC.
//     Centers use normal cached loads (avg 6.5x reuse).
//  2. Single fused kernel: last-finished block does the final reduction
//     (device-scope fence + atomic counter in d_ws, zeroed per call via
//     hipMemsetAsync; fixed-order sum => deterministic).

typedef float f32x4 __attribute__((ext_vector_type(4)));

#define N_SAMPLES 65536
#define DIM 512
#define F4_PER_ROW (DIM / 4)
#define GRID_BLOCKS 2048
#define BLOCK_THREADS 256
#define WAVES_PER_BLOCK 4
#define TOTAL_WAVES (GRID_BLOCKS * WAVES_PER_BLOCK)

__global__ __launch_bounds__(BLOCK_THREADS) void center_loss_fused(
    const float* __restrict__ feature,
    const int* __restrict__ label,
    const float* __restrict__ center,
    float* __restrict__ out,
    float* __restrict__ partial,
    unsigned int* __restrict__ done) {
    __shared__ float wsum[WAVES_PER_BLOCK];
    __shared__ int amLast;

    const int wave = threadIdx.x >> 6;
    const int lane = threadIdx.x & 63;
    const int gw = blockIdx.x * WAVES_PER_BLOCK + wave;

    float acc = 0.0f;

    for (int s = gw; s < N_SAMPLES; s += TOTAL_WAVES) {
        const int lab = label[s];
        const f32x4* fp = reinterpret_cast<const f32x4*>(feature)
                          + (size_t)s * F4_PER_ROW + lane * 2;
        const f32x4* cp = reinterpret_cast<const f32x4*>(center)
                          + (size_t)lab * F4_PER_ROW + lane * 2;
        const f32x4 f0 = __builtin_nontemporal_load(fp);
        const f32x4 f1 = __builtin_nontemporal_load(fp + 1);
        const f32x4 c0 = cp[0];
        const f32x4 c1 = cp[1];

        float ss = 0.0f, d;
        d = f0.x - c0.x; ss = fmaf(d, d, ss);
        d = f0.y - c0.y; ss = fmaf(d, d, ss);
        d = f0.z - c0.z; ss = fmaf(d, d, ss);
        d = f0.w - c0.w; ss = fmaf(d, d, ss);
        d = f1.x - c1.x; ss = fmaf(d, d, ss);
        d = f1.y - c1.y; ss = fmaf(d, d, ss);
        d = f1.z - c1.z; ss = fmaf(d, d, ss);
        d = f1.w - c1.w; ss = fmaf(d, d, ss);

        #pragma unroll
        for (int off = 32; off > 0; off >>= 1)
            ss += __shfl_xor(ss, off, 64);

        if (lane == 0)
            acc += sqrtf(ss);
    }

    if (lane == 0) wsum[wave] = acc;
    __syncthreads();
    if (threadIdx.x == 0) {
        partial[blockIdx.x] = wsum[0] + wsum[1] + wsum[2] + wsum[3];
        __threadfence();  // release partial before signalling
        unsigned int prev = atomicAdd(done, 1u);
        amLast = (prev == GRID_BLOCKS - 1) ? 1 : 0;
    }
    __syncthreads();

    if (amLast) {
        __threadfence();  // acquire side
        float s2 = 0.0f;
        for (int i = threadIdx.x; i < GRID_BLOCKS; i += BLOCK_THREADS)
            s2 += partial[i];
        #pragma unroll
        for (int off = 32; off > 0; off >>= 1)
            s2 += __shfl_xor(s2, off, 64);
        if (lane == 0) wsum[wave] = s2;
        __syncthreads();
        if (threadIdx.x == 0)
            out[0] = (wsum[0] + wsum[1] + wsum[2] + wsum[3]) * (1.0f / (float)N_SAMPLES);
    }
}

extern "C" void kernel_launch(void* const* d_in, const int* in_sizes, int n_in,
                              void* d_out, int out_size, void* d_ws, size_t ws_size,
                              hipStream_t stream) {
    const float* feature = (const float*)d_in[0];
    const int*   label   = (const int*)d_in[1];
    const float* center  = (const float*)d_in[2];
    float* out = (float*)d_out;
    float* partial = (float*)d_ws;                                   // 2048 floats
    unsigned int* done = (unsigned int*)((char*)d_ws + GRID_BLOCKS * sizeof(float));

    // zero the completion counter each call (d_ws not re-poisoned by harness)
    hipMemsetAsync((void*)done, 0, sizeof(unsigned int), stream);

    center_loss_fused<<<GRID_BLOCKS, BLOCK_THREADS, 0, stream>>>(
        feature, label, center, out, partial, done);
}

// Round 10
// 111.936 us; speedup vs baseline: 1.2868x; 1.2868x over previous
//
#include <hip/hip_runtime.h>

// center_loss: loss = (1/N) * sum_i ||feature[i] - center_vector[label[i]]||_2
// N=65536, D=512, C=10000, fp32 in/out.
//
// R3 proven structure (interleaved grid-stride, one wave per sample,
// 64 lanes x 2 float4, CACHED loads — NT bypasses LLC and was a 3x loss,
// R9 FETCH_SIZE evidence) + two changes:
//  1. 2-way ILP: each iteration processes samples (s, s+TOTAL_WAVES) with
//     independent chains; butterflies interleaved. VGPR ~48 (< 64 cliff).
//  2. Fused final reduction: last-finished block sums the 2048 partials
//     (device fence + atomic counter in d_ws, zeroed per call; fixed-order
//     sum -> deterministic). Proven correct in R9.

typedef float f32x4 __attribute__((ext_vector_type(4)));

#define N_SAMPLES 65536
#define DIM 512
#define F4_PER_ROW (DIM / 4)
#define GRID_BLOCKS 2048
#define BLOCK_THREADS 256
#define WAVES_PER_BLOCK 4
#define TOTAL_WAVES (GRID_BLOCKS * WAVES_PER_BLOCK)   // 8192; N/TW = 8 samples/wave

__global__ __launch_bounds__(BLOCK_THREADS) void center_loss_fused(
    const float* __restrict__ feature,
    const int* __restrict__ label,
    const float* __restrict__ center,
    float* __restrict__ out,
    float* __restrict__ partial,
    unsigned int* __restrict__ done) {
    __shared__ float wsum[WAVES_PER_BLOCK];
    __shared__ int amLast;

    const int wave = threadIdx.x >> 6;
    const int lane = threadIdx.x & 63;
    const int gw = blockIdx.x * WAVES_PER_BLOCK + wave;

    const f32x4* fbase = reinterpret_cast<const f32x4*>(feature);
    const f32x4* cbase = reinterpret_cast<const f32x4*>(center);
    const int lo2 = lane * 2;

    float acc = 0.0f;

    // 4 iterations, 2 independent samples each (s, s+TOTAL_WAVES)
    for (int s = gw; s < N_SAMPLES; s += 2 * TOTAL_WAVES) {
        const int sA = s;
        const int sB = s + TOTAL_WAVES;          // N = 8*TOTAL_WAVES, always valid
        const int labA = label[sA];              // wave-uniform -> s_load
        const int labB = label[sB];

        const f32x4* fA = fbase + (size_t)sA * F4_PER_ROW + lo2;
        const f32x4* cA = cbase + (size_t)labA * F4_PER_ROW + lo2;
        const f32x4* fB = fbase + (size_t)sB * F4_PER_ROW + lo2;
        const f32x4* cB = cbase + (size_t)labB * F4_PER_ROW + lo2;

        const f32x4 fA0 = fA[0], fA1 = fA[1];
        const f32x4 cA0 = cA[0], cA1 = cA[1];
        const f32x4 fB0 = fB[0], fB1 = fB[1];
        const f32x4 cB0 = cB[0], cB1 = cB[1];

        float ssA = 0.0f, ssB = 0.0f, d;
        d = fA0.x - cA0.x; ssA = fmaf(d, d, ssA);
        d = fB0.x - cB0.x; ssB = fmaf(d, d, ssB);
        d = fA0.y - cA0.y; ssA = fmaf(d, d, ssA);
        d = fB0.y - cB0.y; ssB = fmaf(d, d, ssB);
        d = fA0.z - cA0.z; ssA = fmaf(d, d, ssA);
        d = fB0.z - cB0.z; ssB = fmaf(d, d, ssB);
        d = fA0.w - cA0.w; ssA = fmaf(d, d, ssA);
        d = fB0.w - cB0.w; ssB = fmaf(d, d, ssB);
        d = fA1.x - cA1.x; ssA = fmaf(d, d, ssA);
        d = fB1.x - cB1.x; ssB = fmaf(d, d, ssB);
        d = fA1.y - cA1.y; ssA = fmaf(d, d, ssA);
        d = fB1.y - cB1.y; ssB = fmaf(d, d, ssB);
        d = fA1.z - cA1.z; ssA = fmaf(d, d, ssA);
        d = fB1.z - cB1.z; ssB = fmaf(d, d, ssB);
        d = fA1.w - cA1.w; ssA = fmaf(d, d, ssA);
        d = fB1.w - cB1.w; ssB = fmaf(d, d, ssB);

        // two independent butterflies, interleaved
        #pragma unroll
        for (int off = 32; off > 0; off >>= 1) {
            ssA += __shfl_xor(ssA, off, 64);
            ssB += __shfl_xor(ssB, off, 64);
        }

        if (lane == 0)
            acc += sqrtf(ssA) + sqrtf(ssB);
    }

    if (lane == 0) wsum[wave] = acc;
    __syncthreads();
    if (threadIdx.x == 0) {
        partial[blockIdx.x] = wsum[0] + wsum[1] + wsum[2] + wsum[3];
        __threadfence();  // release
        unsigned int prev = atomicAdd(done, 1u);
        amLast = (prev == GRID_BLOCKS - 1) ? 1 : 0;
    }
    __syncthreads();

    if (amLast) {
        __threadfence();  // acquire
        float s2 = 0.0f;
        for (int i = threadIdx.x; i < GRID_BLOCKS; i += BLOCK_THREADS)
            s2 += partial[i];
        #pragma unroll
        for (int off = 32; off > 0; off >>= 1)
            s2 += __shfl_xor(s2, off, 64);
        if (lane == 0) wsum[wave] = s2;
        __syncthreads();
        if (threadIdx.x == 0)
            out[0] = (wsum[0] + wsum[1] + wsum[2] + wsum[3]) * (1.0f / (float)N_SAMPLES);
    }
}

extern "C" void kernel_launch(void* const* d_in, const int* in_sizes, int n_in,
                              void* d_out, int out_size, void* d_ws, size_t ws_size,
                              hipStream_t stream) {
    const float* feature = (const float*)d_in[0];
    const int*   label   = (const int*)d_in[1];
    const float* center  = (const float*)d_in[2];
    float* out = (float*)d_out;
    float* partial = (float*)d_ws;                                   // 2048 floats
    unsigned int* done = (unsigned int*)((char*)d_ws + GRID_BLOCKS * sizeof(float));

    hipMemsetAsync((void*)done, 0, sizeof(unsigned int), stream);

    center_loss_fused<<<GRID_BLOCKS, BLOCK_THREADS, 0, stream>>>(
        feature, label, center, out, partial, done);
}

// Round 11
// 44.637 us; speedup vs baseline: 3.2269x; 2.5077x over previous
//
#include <hip/hip_runtime.h>

// center_loss: loss = (1/N) * sum_i ||feature[i] - center_vector[label[i]]||_2
// N=65536, D=512, C=10000, fp32 in/out.
//
// Two-kernel structure (R3, proven 45.3us). Fused last-block reduction is
// BANNED: its device-scope __threadfence + atomic forces per-XCD L2
// writeback/invalidate (non-coherent L2s), thrashing the cache for all
// resident blocks — R9/R10 showed ~173us even with ZERO HBM traffic.
// NT loads BANNED: bypass LLC, feature re-fetched from HBM every replay
// (R9 FETCH_SIZE=124MB).
//
// Single change vs R3: 2-way ILP — each iteration processes samples
// (s, s+TOTAL_WAVES) as independent chains, butterflies interleaved.
// VGPR ~28 (R10 measurement), well under the 64-VGPR occupancy cliff.

typedef float f32x4 __attribute__((ext_vector_type(4)));

#define N_SAMPLES 65536
#define DIM 512
#define F4_PER_ROW (DIM / 4)
#define GRID_BLOCKS 2048
#define BLOCK_THREADS 256
#define WAVES_PER_BLOCK 4
#define TOTAL_WAVES (GRID_BLOCKS * WAVES_PER_BLOCK)   // 8192; 8 samples/wave

__global__ __launch_bounds__(BLOCK_THREADS) void center_loss_pass1(
    const float* __restrict__ feature,
    const int* __restrict__ label,
    const float* __restrict__ center,
    float* __restrict__ partial) {
    __shared__ float wsum[WAVES_PER_BLOCK];

    const int wave = threadIdx.x >> 6;
    const int lane = threadIdx.x & 63;
    const int gw = blockIdx.x * WAVES_PER_BLOCK + wave;

    const f32x4* fbase = reinterpret_cast<const f32x4*>(feature);
    const f32x4* cbase = reinterpret_cast<const f32x4*>(center);
    const int lo2 = lane * 2;

    float acc = 0.0f;

    for (int s = gw; s < N_SAMPLES; s += 2 * TOTAL_WAVES) {
        const int sA = s;
        const int sB = s + TOTAL_WAVES;          // N = 8*TOTAL_WAVES, always valid
        const int labA = label[sA];
        const int labB = label[sB];

        const f32x4* fA = fbase + (size_t)sA * F4_PER_ROW + lo2;
        const f32x4* cA = cbase + (size_t)labA * F4_PER_ROW + lo2;
        const f32x4* fB = fbase + (size_t)sB * F4_PER_ROW + lo2;
        const f32x4* cB = cbase + (size_t)labB * F4_PER_ROW + lo2;

        const f32x4 fA0 = fA[0], fA1 = fA[1];
        const f32x4 cA0 = cA[0], cA1 = cA[1];
        const f32x4 fB0 = fB[0], fB1 = fB[1];
        const f32x4 cB0 = cB[0], cB1 = cB[1];

        float ssA = 0.0f, ssB = 0.0f, d;
        d = fA0.x - cA0.x; ssA = fmaf(d, d, ssA);
        d = fB0.x - cB0.x; ssB = fmaf(d, d, ssB);
        d = fA0.y - cA0.y; ssA = fmaf(d, d, ssA);
        d = fB0.y - cB0.y; ssB = fmaf(d, d, ssB);
        d = fA0.z - cA0.z; ssA = fmaf(d, d, ssA);
        d = fB0.z - cB0.z; ssB = fmaf(d, d, ssB);
        d = fA0.w - cA0.w; ssA = fmaf(d, d, ssA);
        d = fB0.w - cB0.w; ssB = fmaf(d, d, ssB);
        d = fA1.x - cA1.x; ssA = fmaf(d, d, ssA);
        d = fB1.x - cB1.x; ssB = fmaf(d, d, ssB);
        d = fA1.y - cA1.y; ssA = fmaf(d, d, ssA);
        d = fB1.y - cB1.y; ssB = fmaf(d, d, ssB);
        d = fA1.z - cA1.z; ssA = fmaf(d, d, ssA);
        d = fB1.z - cB1.z; ssB = fmaf(d, d, ssB);
        d = fA1.w - cA1.w; ssA = fmaf(d, d, ssA);
        d = fB1.w - cB1.w; ssB = fmaf(d, d, ssB);

        #pragma unroll
        for (int off = 32; off > 0; off >>= 1) {
            ssA += __shfl_xor(ssA, off, 64);
            ssB += __shfl_xor(ssB, off, 64);
        }

        if (lane == 0)
            acc += sqrtf(ssA) + sqrtf(ssB);
    }

    if (lane == 0) wsum[wave] = acc;
    __syncthreads();
    if (threadIdx.x == 0)
        partial[blockIdx.x] = wsum[0] + wsum[1] + wsum[2] + wsum[3];
}

__global__ __launch_bounds__(BLOCK_THREADS) void center_loss_pass2(
    const float* __restrict__ partial,
    float* __restrict__ out) {
    __shared__ float lds[WAVES_PER_BLOCK];
    const int wave = threadIdx.x >> 6;
    const int lane = threadIdx.x & 63;

    float s = 0.0f;
    for (int i = threadIdx.x; i < GRID_BLOCKS; i += BLOCK_THREADS)
        s += partial[i];

    #pragma unroll
    for (int off = 32; off > 0; off >>= 1)
        s += __shfl_xor(s, off, 64);

    if (lane == 0) lds[wave] = s;
    __syncthreads();
    if (threadIdx.x == 0)
        out[0] = (lds[0] + lds[1] + lds[2] + lds[3]) * (1.0f / (float)N_SAMPLES);
}

extern "C" void kernel_launch(void* const* d_in, const int* in_sizes, int n_in,
                              void* d_out, int out_size, void* d_ws, size_t ws_size,
                              hipStream_t stream) {
    const float* feature = (const float*)d_in[0];
    const int*   label   = (const int*)d_in[1];
    const float* center  = (const float*)d_in[2];
    float* out = (float*)d_out;
    float* partial = (float*)d_ws;  // GRID_BLOCKS floats = 8 KB

    center_loss_pass1<<<GRID_BLOCKS, BLOCK_THREADS, 0, stream>>>(feature, label, center, partial);
    center_loss_pass2<<<1, BLOCK_THREADS, 0, stream>>>(partial, out);
}